// Round 8
// baseline (137.631 us; speedup 1.0000x reference)
//
#include <hip/hip_runtime.h>
#include <hip/hip_bf16.h>

#define B_ 1024
#define IN_ 512
#define OUT_ 512
#define BTILE 64
#define OTILE 32
#define ITILE 8
#define KSPLIT 8
#define KCHUNK (IN_ / KSPLIT)          // 64 i's per block
#define NCHUNKS (KCHUNK / ITILE)       // 8 staging chunks
#define P4STRIDE 128  // 32 o * 4 words; b128 writes even 8-phase (free); reads 2-way (free)
#define P2STRIDE 64   // 32 o * 2 words; reads conflict-free; b64 writes 4-phase minimum (free)
#define XSTRIDE 68    // BTILE + 4 pad; stride%8==4 keeps staging writes exactly 2-way (free)

__device__ __forceinline__ float fast_exp2(float x) {
#if __has_builtin(__builtin_amdgcn_exp2f)
    return __builtin_amdgcn_exp2f(x);
#else
    return __exp2f(x);
#endif
}
__device__ __forceinline__ float fast_log2(float x) {
#if __has_builtin(__builtin_amdgcn_logf)
    return __builtin_amdgcn_logf(x);   // v_log_f32 = log2
#else
    return __log2f(x);
#endif
}
__device__ __forceinline__ float fast_cos_rev(float x) {  // cos(2*pi*x), x in revolutions
#if __has_builtin(__builtin_amdgcn_cosf)
    return __builtin_amdgcn_cosf(x);   // v_cos_f32 valid domain +-256 revs; |x| <= ~9 here
#else
    return __cosf(x * 6.2831853071795864f);
#endif
}
__device__ __forceinline__ float fast_rcp(float x) {
#if __has_builtin(__builtin_amdgcn_rcpf)
    return __builtin_amdgcn_rcpf(x);
#else
    return 1.0f / x;
#endif
}

__global__ __launch_bounds__(256, 8) void chirplet_kernel(
    const float* __restrict__ x,
    const float* __restrict__ W,
    const float* __restrict__ Wc,
    const float* __restrict__ S,
    const float* __restrict__ T,
    const float* __restrict__ F,
    const float* __restrict__ bias,
    float* __restrict__ out)
{
    // Total LDS ~10.4 KB -> 8 blocks/CU resident; grid = 8 blocks/CU -> single
    // pass, zero dispatch tail (all blocks co-resident from t=0).
    __shared__ __align__(16) float p4_lds[ITILE * P4STRIDE];  // 4 KB  {a,b',c2,d2}
    __shared__ __align__(16) float p2_lds[ITILE * P2STRIDE];  // 2 KB  {lw,w}
    __shared__ __align__(16) float x_lds[ITILE * XSTRIDE];    // 2.125 KB [i][b]
    __shared__ __align__(16) float s_lds[ITILE * XSTRIDE];    // 2.125 KB silu(x)

    const int tid = threadIdx.x;
    const int o0 = blockIdx.x * OTILE;
    const int b0 = blockIdx.y * BTILE;
    const int k0 = blockIdx.z * KCHUNK;

    // compute mapping: thread = (o pair {oc, oc+16}, 4 consecutive b)
    const int oc = tid & 15;        // 0..15
    const int bq = tid >> 4;        // 0..15 -> b = bq*4 + k

    // x staging: 64 b x 8 i = 512 floats, float2 per thread
    const int xrow = tid >> 2;          // 0..63 (b)
    const int xq   = tid & 3;           // col pair: cols 2*xq, 2*xq+1

    // p staging: 32 o x 8 i = 256 (o,i), exactly one per thread
    const int pol = tid & 31;           // o 0..31
    const int pi  = tid >> 5;           // i 0..7

    const float LOG2E = 1.4426950408889634f;
    const float GK    = 0.8493218002880191f;   // sqrt(0.5*log2(e)); exp(-0.5*u^2)=exp2(-(GK*u)^2)

    float acc[2][4] = {{0.f,0.f,0.f,0.f},{0.f,0.f,0.f,0.f}};

    for (int c = 0; c < NCHUNKS; ++c) {
        const int ib = k0 + c * ITILE;

        // ---- stage x tile (64 b x 8 i): float2 load, silu, transpose to [i][b]
        {
            const float2 v = *(const float2*)(x + (size_t)(b0 + xrow) * IN_ + ib + xq * 2);
            const float xf[2] = { v.x, v.y };
            #pragma unroll
            for (int j = 0; j < 2; ++j) {
                const int col = xq * 2 + j;
                float xv  = xf[j];
                float sig = fast_rcp(1.0f + fast_exp2(-xv * LOG2E));
                x_lds[col * XSTRIDE + xrow] = xv;   // bank 2-way (stride 68)
                s_lds[col * XSTRIDE + xrow] = xv * sig;
            }
        }

        // ---- stage params (32 o x 8 i), one per thread; fold coefficients.
        // sign(Wc) -> cos phase (+0.5 rev); |Wc| -> exp2 offset lw = log2|Wc|.
        {
            const size_t go = (size_t)(o0 + pol) * IN_ + ib + pi;
            const float s  = S[go];
            const float t  = T[go];
            const float f  = F[go];
            const float w  = W[go];
            const float wc = Wc[go];
            const float rs = fast_rcp(s);
            const float a  = f * rs;                       // revolutions per x
            float4 p0; float2 p1;
            p0.x = a;
            p0.y = -a * t + (wc < 0.0f ? 0.5f : 0.0f);     // phase offset + sign(Wc)
            p0.z = rs * GK;
            p0.w = -t * rs * GK;
            p1.x = fast_log2(fabsf(wc));                   // lw
            p1.y = w;
            *(float4*)&p4_lds[pi * P4STRIDE + pol * 4] = p0;
            *(float2*)&p2_lds[pi * P2STRIDE + pol * 2] = p1;
        }
        __syncthreads();

        // ---- compute: each thread 4 b x 2 o over ITILE i's (10 LDS B/elem)
        #pragma unroll 4
        for (int i = 0; i < ITILE; ++i) {
            const float4 ab0 = *(const float4*)&p4_lds[i * P4STRIDE + oc * 4];
            const float4 ab1 = *(const float4*)&p4_lds[i * P4STRIDE + (oc + 16) * 4];
            const float2 lw0 = *(const float2*)&p2_lds[i * P2STRIDE + oc * 2];
            const float2 lw1 = *(const float2*)&p2_lds[i * P2STRIDE + (oc + 16) * 2];
            const float4 xv  = *(const float4*)&x_lds[i * XSTRIDE + bq * 4];
            const float4 svv = *(const float4*)&s_lds[i * XSTRIDE + bq * 4];
            const float xk[4] = { xv.x, xv.y, xv.z, xv.w };
            const float sk[4] = { svv.x, svv.y, svv.z, svv.w };
            const float4 abcd[2] = { ab0, ab1 };
            const float2 lww[2]  = { lw0, lw1 };
            #pragma unroll
            for (int o = 0; o < 2; ++o) {
                #pragma unroll
                for (int k = 0; k < 4; ++k) {
                    float rev = fmaf(abcd[o].x, xk[k], abcd[o].y);   // phase (revs)
                    float co  = fast_cos_rev(rev);                   // +-cos
                    float u   = fmaf(abcd[o].z, xk[k], abcd[o].w);   // GK*(x-t)/s
                    float e   = fast_exp2(fmaf(-u, u, lww[o].x));    // |Wc|*gauss
                    acc[o][k] = fmaf(co, e, acc[o][k]);              // chirplet part
                    acc[o][k] = fmaf(sk[k], lww[o].y, acc[o][k]);    // silu(x)*W
                }
            }
        }
        __syncthreads();
    }

    // ---- epilogue: bias (once, from kslice 0) + fp32 atomic accumulate
    const float badd0 = (blockIdx.z == 0) ? bias[o0 + oc] : 0.0f;
    const float badd1 = (blockIdx.z == 0) ? bias[o0 + oc + 16] : 0.0f;
    #pragma unroll
    for (int k = 0; k < 4; ++k) {
        const int b = b0 + bq * 4 + k;
        float* dst0 = &out[(size_t)b * OUT_ + o0 + oc];
        float* dst1 = &out[(size_t)b * OUT_ + o0 + oc + 16];
#if defined(__HIP_DEVICE_COMPILE__)
        unsafeAtomicAdd(dst0, acc[0][k] + badd0);   // HW global_atomic_add_f32
        unsafeAtomicAdd(dst1, acc[1][k] + badd1);
#else
        atomicAdd(dst0, acc[0][k] + badd0);
        atomicAdd(dst1, acc[1][k] + badd1);
#endif
    }
}

extern "C" void kernel_launch(void* const* d_in, const int* in_sizes, int n_in,
                              void* d_out, int out_size, void* d_ws, size_t ws_size,
                              hipStream_t stream) {
    const float* x    = (const float*)d_in[0];
    const float* W    = (const float*)d_in[1];
    const float* Wc   = (const float*)d_in[2];
    const float* S    = (const float*)d_in[3];
    const float* T    = (const float*)d_in[4];
    const float* F    = (const float*)d_in[5];
    const float* bias = (const float*)d_in[6];
    float* out = (float*)d_out;

    // d_out is poisoned before every launch; atomics need zeroed destination
    hipMemsetAsync(out, 0, (size_t)out_size * sizeof(float), stream);

    dim3 grid(OUT_ / OTILE, B_ / BTILE, KSPLIT);   // 16 x 16 x 8 = 2048 blocks = 8/CU
    chirplet_kernel<<<grid, 256, 0, stream>>>(x, W, Wc, S, T, F, bias, out);
}

// Round 9
// 128.899 us; speedup vs baseline: 1.0677x; 1.0677x over previous
//
#include <hip/hip_runtime.h>
#include <hip/hip_bf16.h>

#define B_ 1024
#define IN_ 512
#define OUT_ 512
#define BTILE 64
#define OTILE 32
#define ITILE 8
#define KSPLIT 16
#define KCHUNK (IN_ / KSPLIT)          // 32 i's per block
#define NCHUNKS (KCHUNK / ITILE)       // 4 staging chunks
#define P4STRIDE 128  // 32 o * 4 words; b128 writes even 8-phase (free); reads 2-way (free)
#define P2STRIDE 64   // 32 o * 2 words; reads conflict-free; b64 writes 4-phase minimum (free)
#define XSTRIDE 68    // BTILE + 4 pad; staging writes exactly 2-way (free)

typedef float v2f __attribute__((ext_vector_type(2)));
#define PKFMA(a, b, c) __builtin_elementwise_fma((v2f)(a), (v2f)(b), (v2f)(c))

__device__ __forceinline__ float fast_exp2(float x) {
#if __has_builtin(__builtin_amdgcn_exp2f)
    return __builtin_amdgcn_exp2f(x);
#else
    return __exp2f(x);
#endif
}
__device__ __forceinline__ float fast_log2(float x) {
#if __has_builtin(__builtin_amdgcn_logf)
    return __builtin_amdgcn_logf(x);   // v_log_f32 = log2
#else
    return __log2f(x);
#endif
}
__device__ __forceinline__ float fast_cos_rev(float x) {  // cos(2*pi*x), x in revolutions
#if __has_builtin(__builtin_amdgcn_cosf)
    return __builtin_amdgcn_cosf(x);   // v_cos_f32 valid domain +-256 revs; |x| <= ~9 here
#else
    return __cosf(x * 6.2831853071795864f);
#endif
}
__device__ __forceinline__ float fast_rcp(float x) {
#if __has_builtin(__builtin_amdgcn_rcpf)
    return __builtin_amdgcn_rcpf(x);
#else
    return 1.0f / x;
#endif
}

__global__ __launch_bounds__(256, 8) void chirplet_kernel(
    const float* __restrict__ x,
    const float* __restrict__ W,
    const float* __restrict__ Wc,
    const float* __restrict__ S,
    const float* __restrict__ T,
    const float* __restrict__ F,
    const float* __restrict__ bias,
    float* __restrict__ out)
{
    // ~10.4 KB LDS, conflict-free (R8 audit). Grid = 16 blocks/CU queued:
    // 2x oversubscription beats exact-fit on this HW (R6 vs R8 measured).
    __shared__ __align__(16) float p4_lds[ITILE * P4STRIDE];  // 4 KB  {a,b',c2,d2}
    __shared__ __align__(16) float p2_lds[ITILE * P2STRIDE];  // 2 KB  {lw,w}
    __shared__ __align__(16) float x_lds[ITILE * XSTRIDE];    // 2.125 KB [i][b]
    __shared__ __align__(16) float s_lds[ITILE * XSTRIDE];    // 2.125 KB silu(x)

    const int tid = threadIdx.x;
    const int o0 = blockIdx.x * OTILE;
    const int b0 = blockIdx.y * BTILE;
    const int k0 = blockIdx.z * KCHUNK;

    // compute mapping: thread = (o pair {oc, oc+16}, 4 consecutive b)
    const int oc = tid & 15;        // 0..15
    const int bq = tid >> 4;        // 0..15 -> b = bq*4 + k

    // x staging: 64 b x 8 i = 512 floats, float2 per thread
    const int xrow = tid >> 2;          // 0..63 (b)
    const int xq   = tid & 3;           // col pair: cols 2*xq, 2*xq+1

    // p staging: 32 o x 8 i = 256 (o,i), exactly one per thread
    const int pol = tid & 31;           // o 0..31
    const int pi  = tid >> 5;           // i 0..7

    const float LOG2E = 1.4426950408889634f;
    const float GK    = 0.8493218002880191f;   // sqrt(0.5*log2(e)); exp(-0.5*u^2)=exp2(-(GK*u)^2)

    v2f acc2[2][2] = {{{0.f,0.f},{0.f,0.f}},{{0.f,0.f},{0.f,0.f}}};

    for (int c = 0; c < NCHUNKS; ++c) {
        const int ib = k0 + c * ITILE;

        // ---- stage x tile (64 b x 8 i): float2 load, silu, transpose to [i][b]
        {
            const float2 v = *(const float2*)(x + (size_t)(b0 + xrow) * IN_ + ib + xq * 2);
            const float xf[2] = { v.x, v.y };
            #pragma unroll
            for (int j = 0; j < 2; ++j) {
                const int col = xq * 2 + j;
                float xv  = xf[j];
                float sig = fast_rcp(1.0f + fast_exp2(-xv * LOG2E));
                x_lds[col * XSTRIDE + xrow] = xv;
                s_lds[col * XSTRIDE + xrow] = xv * sig;
            }
        }

        // ---- stage params (32 o x 8 i), one per thread; fold coefficients.
        // sign(Wc) -> cos phase (+0.5 rev); |Wc| -> exp2 offset lw = log2|Wc|.
        {
            const size_t go = (size_t)(o0 + pol) * IN_ + ib + pi;
            const float s  = S[go];
            const float t  = T[go];
            const float f  = F[go];
            const float w  = W[go];
            const float wc = Wc[go];
            const float rs = fast_rcp(s);
            const float a  = f * rs;                       // revolutions per x
            float4 p0; float2 p1;
            p0.x = a;
            p0.y = -a * t + (wc < 0.0f ? 0.5f : 0.0f);     // phase offset + sign(Wc)
            p0.z = rs * GK;
            p0.w = -t * rs * GK;
            p1.x = fast_log2(fabsf(wc));                   // lw
            p1.y = w;
            *(float4*)&p4_lds[pi * P4STRIDE + pol * 4] = p0;
            *(float2*)&p2_lds[pi * P2STRIDE + pol * 2] = p1;
        }
        __syncthreads();

        // ---- compute: 4 b x 2 o per thread; full-rate math packed (v_pk_fma_f32)
        #pragma unroll 4
        for (int i = 0; i < ITILE; ++i) {
            const float4 abcd[2] = {
                *(const float4*)&p4_lds[i * P4STRIDE + oc * 4],
                *(const float4*)&p4_lds[i * P4STRIDE + (oc + 16) * 4] };
            const float2 lww[2] = {
                *(const float2*)&p2_lds[i * P2STRIDE + oc * 2],
                *(const float2*)&p2_lds[i * P2STRIDE + (oc + 16) * 2] };
            const v2f* xp = (const v2f*)&x_lds[i * XSTRIDE + bq * 4];
            const v2f* sp = (const v2f*)&s_lds[i * XSTRIDE + bq * 4];
            const v2f xk2[2] = { xp[0], xp[1] };
            const v2f sk2[2] = { sp[0], sp[1] };
            #pragma unroll
            for (int o = 0; o < 2; ++o) {
                const v2f aa = { abcd[o].x, abcd[o].x };
                const v2f bb = { abcd[o].y, abcd[o].y };
                const v2f cc = { abcd[o].z, abcd[o].z };
                const v2f dd = { abcd[o].w, abcd[o].w };
                const v2f lw = { lww[o].x, lww[o].x };
                const v2f wv = { lww[o].y, lww[o].y };
                #pragma unroll
                for (int p = 0; p < 2; ++p) {
                    v2f rev = PKFMA(aa, xk2[p], bb);       // phase (revs), packed
                    v2f u   = PKFMA(cc, xk2[p], dd);       // GK*(x-t)/s, packed
                    v2f arg = PKFMA(-u, u, lw);            // lw - u^2, packed
                    v2f co, e;
                    co.x = fast_cos_rev(rev.x);            // trans: scalar pipe
                    co.y = fast_cos_rev(rev.y);
                    e.x  = fast_exp2(arg.x);
                    e.y  = fast_exp2(arg.y);
                    acc2[o][p] = PKFMA(co, e, acc2[o][p]); // chirplet, packed
                    acc2[o][p] = PKFMA(sk2[p], wv, acc2[o][p]); // silu*W, packed
                }
            }
        }
        __syncthreads();
    }

    // ---- epilogue: bias (once, from kslice 0) + fp32 atomic accumulate
    const float badd0 = (blockIdx.z == 0) ? bias[o0 + oc] : 0.0f;
    const float badd1 = (blockIdx.z == 0) ? bias[o0 + oc + 16] : 0.0f;
    const float badd[2] = { badd0, badd1 };
    #pragma unroll
    for (int o = 0; o < 2; ++o) {
        #pragma unroll
        for (int p = 0; p < 2; ++p) {
            #pragma unroll
            for (int j = 0; j < 2; ++j) {
                const int b = b0 + bq * 4 + p * 2 + j;
                float* dst = &out[(size_t)b * OUT_ + o0 + oc + o * 16];
                const float val = (j == 0 ? acc2[o][p].x : acc2[o][p].y) + badd[o];
#if defined(__HIP_DEVICE_COMPILE__)
                unsafeAtomicAdd(dst, val);   // HW global_atomic_add_f32
#else
                atomicAdd(dst, val);
#endif
            }
        }
    }
}

extern "C" void kernel_launch(void* const* d_in, const int* in_sizes, int n_in,
                              void* d_out, int out_size, void* d_ws, size_t ws_size,
                              hipStream_t stream) {
    const float* x    = (const float*)d_in[0];
    const float* W    = (const float*)d_in[1];
    const float* Wc   = (const float*)d_in[2];
    const float* S    = (const float*)d_in[3];
    const float* T    = (const float*)d_in[4];
    const float* F    = (const float*)d_in[5];
    const float* bias = (const float*)d_in[6];
    float* out = (float*)d_out;

    // d_out is poisoned before every launch; atomics need zeroed destination
    hipMemsetAsync(out, 0, (size_t)out_size * sizeof(float), stream);

    dim3 grid(OUT_ / OTILE, B_ / BTILE, KSPLIT);   // 16 x 16 x 16 = 4096 blocks
    chirplet_kernel<<<grid, 256, 0, stream>>>(x, W, Wc, S, T, F, bias, out);
}